// Round 2
// baseline (450.193 us; speedup 1.0000x reference)
//
#include <hip/hip_runtime.h>
#include <math.h>

#define T_ 256
#define B_ 128
#define D_ 1024
#define K_ 21

// ---------------------------------------------------------------------------
// Kernel 1: FC projection  fc[row][k] = dot(A[row,:], W[:,k]) + b[k]
// row = t*B + b (32768 rows). Lane = row within a 64-row block-tile.
// Wave 0 covers d in [0,512), wave 1 covers [512,1024); LDS reduce at end.
// W[d][k] is wave-uniform -> compiler emits s_load (scalar broadcast path).
// Also writes ee = exp(fc) for the linear-domain forward scan.
// ---------------------------------------------------------------------------
__global__ __launch_bounds__(128) void fc_kernel(
    const float* __restrict__ A, const float* __restrict__ W,
    const float* __restrict__ bias, float* __restrict__ fc,
    float* __restrict__ ee) {
  __shared__ float red[64][23];  // pad 23 (odd) -> conflict-free
  const int lane = threadIdx.x & 63;
  const int wave = threadIdx.x >> 6;
  const int row = blockIdx.x * 64 + lane;
  const float* Arow = A + (size_t)row * D_;

  float acc[K_];
#pragma unroll
  for (int k = 0; k < K_; ++k) acc[k] = 0.f;

  const int d0 = wave * (D_ / 2);
  for (int d = d0; d < d0 + D_ / 2; d += 4) {
    const float4 a4 = *(const float4*)(Arow + d);
    const float* Wp = W + d * K_;  // uniform address -> s_load
#pragma unroll
    for (int k = 0; k < K_; ++k) acc[k] = fmaf(a4.x, Wp[k], acc[k]);
#pragma unroll
    for (int k = 0; k < K_; ++k) acc[k] = fmaf(a4.y, Wp[K_ + k], acc[k]);
#pragma unroll
    for (int k = 0; k < K_; ++k) acc[k] = fmaf(a4.z, Wp[2 * K_ + k], acc[k]);
#pragma unroll
    for (int k = 0; k < K_; ++k) acc[k] = fmaf(a4.w, Wp[3 * K_ + k], acc[k]);
  }

  if (wave == 1) {
#pragma unroll
    for (int k = 0; k < K_; ++k) red[lane][k] = acc[k];
  }
  __syncthreads();
  if (wave == 0) {
    float* o1 = fc + (size_t)row * K_;
    float* o2 = ee + (size_t)row * K_;
#pragma unroll
    for (int k = 0; k < K_; ++k) {
      const float v = acc[k] + red[lane][k] + bias[k];
      o1[k] = v;
      o2[k] = __expf(v);
    }
  }
}

// ---------------------------------------------------------------------------
// Kernel 2: the two sequential scans, one wave (64 threads) per batch elem.
//   blocks [0,128): CRF forward (denominator), linear domain w/ renorm
//   blocks [128,256): Viterbi forward + fused LDS backtrack
// Lane j (0..20) owns tag-column j; lanes 21..63 duplicate lane 20 (never
// read). Cross-lane broadcast of the 21 scores via __shfl (ds_bpermute).
// ---------------------------------------------------------------------------
__global__ __launch_bounds__(64) void scan_kernel(
    const float* __restrict__ fc, const float* __restrict__ ee,
    const int* __restrict__ tags, const float* __restrict__ startT,
    const float* __restrict__ endT, const float* __restrict__ trans,
    float* __restrict__ out_tags, float* __restrict__ loss) {
  __shared__ unsigned char hist[T_ - 1][24];
  const int lane = threadIdx.x;
  const int jc = lane < K_ ? lane : K_ - 1;  // clamped column (dup lanes)

  if (blockIdx.x < B_) {
    // ---------------- forward / denominator ----------------
    const int b = blockIdx.x;
    float etcol[K_];
#pragma unroll
    for (int i = 0; i < K_; ++i) etcol[i] = __expf(trans[i * K_ + jc]);

    float p = __expf(startT[jc]) * ee[(size_t)b * K_ + jc];  // exp(start+em0)
    float L = 0.f;

    for (int t = 1; t < T_; ++t) {
      const float eet = ee[((size_t)t * B_ + b) * K_ + jc];
      const bool m = tags[t * B_ + b] != 0;
      float s[K_];
#pragma unroll
      for (int i = 0; i < K_; ++i) s[i] = __shfl(p, i, 64);
      float dA = 0.f, dB = 0.f, dC = 0.f, SA = 0.f, SB = 0.f, SC = 0.f;
#pragma unroll
      for (int i = 0; i < K_; i += 3) {
        dA = fmaf(s[i], etcol[i], dA);
        dB = fmaf(s[i + 1], etcol[i + 1], dB);
        dC = fmaf(s[i + 2], etcol[i + 2], dC);
        SA += s[i];
        SB += s[i + 1];
        SC += s[i + 2];
      }
      const float S = SA + SB + SC;
      const float dot = dA + dB + dC;
      const float pn = dot * __builtin_amdgcn_rcpf(S) * eet;
      p = m ? pn : p;
      L += m ? __logf(S) : 0.f;
    }
    // den_b = L + log(sum_j p[j]*exp(end[j]))
    const float w = p * __expf(endT[jc]);
    float tot = 0.f;
#pragma unroll
    for (int i = 0; i < K_; ++i) tot += __shfl(w, i, 64);
    if (lane == 0) atomicAdd(loss, L + __logf(tot));
  } else {
    // ---------------- Viterbi ----------------
    const int b = blockIdx.x - B_;
    float tcol[K_];
#pragma unroll
    for (int i = 0; i < K_; ++i) tcol[i] = trans[i * K_ + jc];

    float sc = startT[jc] + fc[(size_t)b * K_ + jc];

    for (int t = 1; t < T_; ++t) {
      const float emt = fc[((size_t)t * B_ + b) * K_ + jc];
      const bool m = tags[t * B_ + b] != 0;
      float s[K_], c[K_];
#pragma unroll
      for (int i = 0; i < K_; ++i) s[i] = __shfl(sc, i, 64);
#pragma unroll
      for (int i = 0; i < K_; ++i) c[i] = s[i] + tcol[i];
      float mA = c[0], mB = c[1], mC = c[2];
#pragma unroll
      for (int i = 3; i < K_; i += 3) {
        mA = fmaxf(mA, c[i]);
        mB = fmaxf(mB, c[i + 1]);
        mC = fmaxf(mC, c[i + 2]);
      }
      const float mx = fmaxf(mA, fmaxf(mB, mC));
      int idx = 0;
#pragma unroll
      for (int i = K_ - 1; i >= 0; --i) idx = (c[i] == mx) ? i : idx;  // first argmax
      const float nxt = mx + emt;
      const int ptr = m ? idx : jc;
      sc = m ? nxt : sc;
      if (lane < K_) hist[t - 1][lane] = (unsigned char)ptr;
    }
    __syncthreads();  // LDS writes visible to lane 0 (single wave, cheap)

    const float fin = sc + endT[jc];
    float s[K_];
#pragma unroll
    for (int i = 0; i < K_; ++i) s[i] = __shfl(fin, i, 64);
    float mA = s[0], mB = s[1], mC = s[2];
#pragma unroll
    for (int i = 3; i < K_; i += 3) {
      mA = fmaxf(mA, s[i]);
      mB = fmaxf(mB, s[i + 1]);
      mC = fmaxf(mC, s[i + 2]);
    }
    const float mx = fmaxf(mA, fmaxf(mB, mC));
    int last = 0;
#pragma unroll
    for (int i = K_ - 1; i >= 0; --i) last = (s[i] == mx) ? i : last;

    if (lane == 0) {
      int cur = last;
      for (int t = T_ - 1; t >= 1; --t) {
        out_tags[t * B_ + b] = (tags[t * B_ + b] != 0) ? (float)cur : 0.f;
        cur = hist[t - 1][cur];
      }
      out_tags[b] = (float)cur;  // t = 0: mask always true (lengths >= T/2)
    }
  }
}

// ---------------------------------------------------------------------------
// Kernel 3: numerator (gold-path score), one block per batch, thread = t.
// num_b = start[tag0]+em0 + sum_{t>=1,mask} (trans[tag_{t-1},tag_t]+em_t)
//         + end[tag_last].  atomicAdd(-num_b) into loss accumulator.
// ---------------------------------------------------------------------------
__global__ __launch_bounds__(256) void num_kernel(
    const float* __restrict__ fc, const int* __restrict__ tags,
    const float* __restrict__ startT, const float* __restrict__ endT,
    const float* __restrict__ trans, float* __restrict__ loss) {
  const int b = blockIdx.x, t = threadIdx.x;
  const int tg = tags[t * B_ + b];
  const bool m = tg != 0;
  float contrib = 0.f;
  if (t == 0) {
    contrib = startT[tg] + fc[(size_t)b * K_ + tg];
  } else if (m) {
    const int pg = tags[(t - 1) * B_ + b];
    contrib = trans[pg * K_ + tg] + fc[((size_t)t * B_ + b) * K_ + tg];
  }
  // last valid step: mask monotone (t < length), so last = m && next invalid
  const bool isLast = m && (t == T_ - 1 || tags[(t + 1) * B_ + b] == 0);
  if (isLast) contrib += endT[tg];

#pragma unroll
  for (int off = 32; off > 0; off >>= 1) contrib += __shfl_down(contrib, off, 64);
  __shared__ float wsum[4];
  if ((threadIdx.x & 63) == 0) wsum[threadIdx.x >> 6] = contrib;
  __syncthreads();
  if (threadIdx.x == 0)
    atomicAdd(loss, -(wsum[0] + wsum[1] + wsum[2] + wsum[3]));
}

// Kernel 4: copy accumulated loss (float) into the float32 output slot.
__global__ void fin_kernel(const float* __restrict__ loss, float* __restrict__ o) {
  if (threadIdx.x == 0) o[0] = loss[0];
}

extern "C" void kernel_launch(void* const* d_in, const int* in_sizes, int n_in,
                              void* d_out, int out_size, void* d_ws,
                              size_t ws_size, hipStream_t stream) {
  const float* A = (const float*)d_in[0];       // (T,B,D) f32
  const int* tags = (const int*)d_in[1];        // (T,B) i32
  const float* W = (const float*)d_in[2];       // (D,K) f32
  const float* bias = (const float*)d_in[3];    // (K,)
  const float* startT = (const float*)d_in[4];  // (K,)
  const float* endT = (const float*)d_in[5];    // (K,)
  const float* trans = (const float*)d_in[6];   // (K,K)

  float* out_tags = (float*)d_out;                  // (T,B) as float32
  float* out_loss = (float*)d_out + (size_t)T_ * B_;  // slot 32768

  float* fc = (float*)d_ws;                      // T*B*K f32
  float* ee = fc + (size_t)T_ * B_ * K_;         // T*B*K f32
  float* loss = ee + (size_t)T_ * B_ * K_;       // 1 f32 accumulator

  hipMemsetAsync(loss, 0, sizeof(float), stream);
  fc_kernel<<<512, 128, 0, stream>>>(A, W, bias, fc, ee);
  scan_kernel<<<256, 64, 0, stream>>>(fc, ee, tags, startT, endT, trans,
                                      out_tags, loss);
  num_kernel<<<128, 256, 0, stream>>>(fc, tags, startT, endT, trans, loss);
  fin_kernel<<<1, 64, 0, stream>>>(loss, out_loss);
}